// Round 4
// baseline (464.036 us; speedup 1.0000x reference)
//
#include <hip/hip_runtime.h>
#include <hip/hip_bf16.h>

// B=4, T=2048, E=768, H=12, hd=64.
// Round 4: de-staged attention (K/V frags straight from L2, no barriers).
//   p1: xb = bf16(x)                      [8192][768]
//   p2: wqkv_t = bf16(Wqkv^T)             [2304][768]
//   p3: wproj_t = bf16(Wproj^T)           [768][768]
//   k1: qkv MFMA GEMM -> bf16 q,k [B,H,T,64], v^T [B,H,64,T]
//   k2: MFMA flash attention (no LDS staging) -> bf16 [B,T,E]
//   k3: proj MFMA GEMM -> f32 out

#define BB 4
#define TT 2048
#define EE 768
#define HH 12
#define HD 64
#define KK 768
#define BTE (BB*TT*EE)  // 6291456

typedef __attribute__((ext_vector_type(8))) short bf16x8;
typedef __attribute__((ext_vector_type(4))) float f32x4;

static __device__ __forceinline__ unsigned short f2bf(float f) {
    unsigned u = __builtin_bit_cast(unsigned, f);
    u += 0x7fffu + ((u >> 16) & 1u);   // RNE
    return (unsigned short)(u >> 16);
}

// ---------------------------------------------------------------------------
// x f32 -> bf16, 8 elems/thread
// ---------------------------------------------------------------------------
__global__ __launch_bounds__(256)
void convx_kernel(const float* __restrict__ x, unsigned short* __restrict__ xb) {
    const size_t i = ((size_t)blockIdx.x * 256 + threadIdx.x) * 8;
    float4 a = *(const float4*)&x[i];
    float4 b = *(const float4*)&x[i + 4];
    ushort4 lo, hi;
    lo.x = f2bf(a.x); lo.y = f2bf(a.y); lo.z = f2bf(a.z); lo.w = f2bf(a.w);
    hi.x = f2bf(b.x); hi.y = f2bf(b.y); hi.z = f2bf(b.z); hi.w = f2bf(b.w);
    *(ushort4*)&xb[i] = lo;
    *(ushort4*)&xb[i + 4] = hi;
}

// ---------------------------------------------------------------------------
// W[768][N] f32 -> Wt[N][768] bf16 (64x64 tiles via LDS)
// ---------------------------------------------------------------------------
__global__ __launch_bounds__(256)
void transw_kernel(const float* __restrict__ W, unsigned short* __restrict__ Wt, int N) {
    __shared__ unsigned short Ts[64][72];
    const int n0 = blockIdx.x * 64;
    const int k0 = blockIdx.y * 64;
    const int tid = threadIdx.x;
    {
        const int r = tid >> 4;
        const int c4 = (tid & 15) << 2;
#pragma unroll
        for (int i = 0; i < 4; ++i) {
            const int k = r + i * 16;
            float4 w4 = *(const float4*)&W[(size_t)(k0 + k) * N + n0 + c4];
            Ts[k][c4 + 0] = f2bf(w4.x); Ts[k][c4 + 1] = f2bf(w4.y);
            Ts[k][c4 + 2] = f2bf(w4.z); Ts[k][c4 + 3] = f2bf(w4.w);
        }
    }
    __syncthreads();
#pragma unroll
    for (int i = 0; i < 2; ++i) {
        const int idx = tid + i * 256;
        const int n = idx >> 3;
        const int ch = idx & 7;
        ushort4 p0, p1;
        p0.x = Ts[ch * 8 + 0][n]; p0.y = Ts[ch * 8 + 1][n];
        p0.z = Ts[ch * 8 + 2][n]; p0.w = Ts[ch * 8 + 3][n];
        p1.x = Ts[ch * 8 + 4][n]; p1.y = Ts[ch * 8 + 5][n];
        p1.z = Ts[ch * 8 + 6][n]; p1.w = Ts[ch * 8 + 7][n];
        *(ushort4*)&Wt[(size_t)(n0 + n) * KK + k0 + ch * 8] = p0;
        *(ushort4*)&Wt[(size_t)(n0 + n) * KK + k0 + ch * 8 + 4] = p1;
    }
}

// ---------------------------------------------------------------------------
// bf16 MFMA GEMM: C[M][N] = A[M][768] @ Wt[N][768]^T
// 128x128 tile, BK=32, 256 thr = 4 waves (2x2), acc 4x4 frags of 16x16x32.
// MODE 0: qkv scatter epilogue. MODE 1: f32 row-major out.
// ---------------------------------------------------------------------------
template<int MODE>
__global__ __launch_bounds__(256)
void mfma_gemm_kernel(const unsigned short* __restrict__ A,
                      const unsigned short* __restrict__ Wt,
                      unsigned short* __restrict__ q_ws,
                      unsigned short* __restrict__ k_ws,
                      unsigned short* __restrict__ v_ws,
                      float* __restrict__ outf) {
    __shared__ __align__(16) unsigned short As[128 * 40];   // pad: 80 B rows
    __shared__ __align__(16) unsigned short Bs[128 * 40];
    const int bx = blockIdx.x;
    const int by = blockIdx.y;
    const int tid = threadIdx.x;
    const int w = tid >> 6, lane = tid & 63;
    const int c = lane & 15, g = lane >> 4;
    const int wr = w >> 1, wc = w & 1;
    const int m0 = by * 128, n0 = bx * 128;

    const int r0 = tid >> 2;       // 0..63
    const int ch = tid & 3;        // 8-elem chunk

    const unsigned short* Ap = A  + (size_t)m0 * KK;
    const unsigned short* Bp = Wt + (size_t)n0 * KK;

    f32x4 acc[4][4] = {};

    for (int kt = 0; kt < KK / 32; ++kt) {
        const int k0 = kt * 32;
        const uint4 a0 = *(const uint4*)&Ap[(size_t)r0 * KK + k0 + ch * 8];
        const uint4 a1 = *(const uint4*)&Ap[(size_t)(r0 + 64) * KK + k0 + ch * 8];
        const uint4 b0 = *(const uint4*)&Bp[(size_t)r0 * KK + k0 + ch * 8];
        const uint4 b1 = *(const uint4*)&Bp[(size_t)(r0 + 64) * KK + k0 + ch * 8];
        __syncthreads();
        *(uint4*)&As[r0 * 40 + ch * 8]        = a0;
        *(uint4*)&As[(r0 + 64) * 40 + ch * 8] = a1;
        *(uint4*)&Bs[r0 * 40 + ch * 8]        = b0;
        *(uint4*)&Bs[(r0 + 64) * 40 + ch * 8] = b1;
        __syncthreads();

        bf16x8 af[4], bfr[4];
#pragma unroll
        for (int m = 0; m < 4; ++m)
            af[m] = *(const bf16x8*)&As[(wr * 64 + m * 16 + c) * 40 + g * 8];
#pragma unroll
        for (int n = 0; n < 4; ++n)
            bfr[n] = *(const bf16x8*)&Bs[(wc * 64 + n * 16 + c) * 40 + g * 8];
#pragma unroll
        for (int m = 0; m < 4; ++m)
#pragma unroll
            for (int n = 0; n < 4; ++n)
                acc[m][n] = __builtin_amdgcn_mfma_f32_16x16x32_bf16(af[m], bfr[n], acc[m][n], 0, 0, 0);
    }

    if (MODE == 0) {
        const int which = n0 / EE;
        const int h = (n0 % EE) / HD + wc;
        const int b = m0 / TT;
        const int tb = (m0 % TT) + wr * 64;
        if (which < 2) {
            unsigned short* dst = (which == 0) ? q_ws : k_ws;
            unsigned short* base = dst + (((size_t)b * HH + h) * TT) * HD;
#pragma unroll
            for (int m = 0; m < 4; ++m)
#pragma unroll
                for (int n = 0; n < 4; ++n)
#pragma unroll
                    for (int j = 0; j < 4; ++j)
                        base[(size_t)(tb + m * 16 + 4 * g + j) * HD + n * 16 + c] =
                            f2bf(acc[m][n][j]);
        } else {
            unsigned short* base = v_ws + (((size_t)b * HH + h) * HD) * TT;
#pragma unroll
            for (int m = 0; m < 4; ++m)
#pragma unroll
                for (int n = 0; n < 4; ++n)
#pragma unroll
                    for (int j = 0; j < 4; ++j)
                        base[(size_t)(n * 16 + c) * TT + tb + m * 16 + 4 * g + j] =
                            f2bf(acc[m][n][j]);
        }
    } else {
#pragma unroll
        for (int m = 0; m < 4; ++m)
#pragma unroll
            for (int n = 0; n < 4; ++n)
#pragma unroll
                for (int j = 0; j < 4; ++j)
                    outf[(size_t)(m0 + wr * 64 + m * 16 + 4 * g + j) * EE
                         + n0 + wc * 64 + n * 16 + c] = acc[m][n][j];
    }
}

// ---------------------------------------------------------------------------
// MFMA flash attention, de-staged: K/V fragments read directly from global
// (K/V per head = 256 KB each -> L2-resident). LDS only holds the wave-
// private P buffer; NO __syncthreads anywhere. 4 independent waves/block,
// wave w owns q rows [qi*64 + w*16, +16).
// ---------------------------------------------------------------------------
__global__ __launch_bounds__(256)
void attn_kernel(const unsigned short* __restrict__ q,
                 const unsigned short* __restrict__ k,
                 const unsigned short* __restrict__ vt,
                 unsigned short* __restrict__ attn_b) {
    __shared__ __align__(16) unsigned short Pb[4 * 16 * 72];

    const int qi = (TT / 64 - 1) - blockIdx.x;   // heavy blocks first
    const int h = blockIdx.y, b = blockIdx.z;
    const int tid = threadIdx.x;
    const int w = tid >> 6;
    const int lane = tid & 63;
    const int c = lane & 15;
    const int g = lane >> 4;

    const size_t head_off = (size_t)(b * HH + h) * TT * HD;
    const unsigned short* qp = q + head_off;
    const unsigned short* kp = k + head_off;
    const unsigned short* vp = vt + head_off;   // [64][T]

    const int q0 = qi * 64 + w * 16;

    const bf16x8 qa0 = *(const bf16x8*)&qp[(size_t)(q0 + c) * HD + g * 8];
    const bf16x8 qa1 = *(const bf16x8*)&qp[(size_t)(q0 + c) * HD + 32 + g * 8];

    unsigned short* Pw = &Pb[w * 16 * 72];

    f32x4 o[4] = {};
    float m_r[4], l_r[4];
#pragma unroll
    for (int r = 0; r < 4; ++r) { m_r[r] = -INFINITY; l_r[r] = 0.f; }

    for (int kt = 0; kt <= qi; ++kt) {
        const int kv0 = kt * 64;

        // K fragments straight from global (rows contiguous -> coalesced)
        bf16x8 kf0[4], kf1[4];
#pragma unroll
        for (int kb = 0; kb < 4; ++kb) {
            const unsigned short* kr = &kp[(size_t)(kv0 + kb * 16 + c) * HD];
            kf0[kb] = *(const bf16x8*)&kr[g * 8];
            kf1[kb] = *(const bf16x8*)&kr[32 + g * 8];
        }
        // V fragments issued now; consumed after softmax (latency hidden)
        bf16x8 vf0[4], vf1[4];
#pragma unroll
        for (int db = 0; db < 4; ++db) {
            const unsigned short* vr = &vp[(size_t)(db * 16 + c) * TT + kv0];
            vf0[db] = *(const bf16x8*)&vr[g * 8];
            vf1[db] = *(const bf16x8*)&vr[32 + g * 8];
        }

        f32x4 s[4];
        __builtin_amdgcn_s_setprio(1);
#pragma unroll
        for (int kb = 0; kb < 4; ++kb) {
            f32x4 z = {0.f, 0.f, 0.f, 0.f};
            z = __builtin_amdgcn_mfma_f32_16x16x32_bf16(qa0, kf0[kb], z, 0, 0, 0);
            s[kb] = __builtin_amdgcn_mfma_f32_16x16x32_bf16(qa1, kf1[kb], z, 0, 0, 0);
        }
        __builtin_amdgcn_s_setprio(0);

        // ---- online softmax (D layout: row q = 4g+r, col key = kb*16+c) ----
        float mx[4] = {-INFINITY, -INFINITY, -INFINITY, -INFINITY};
        if (kt == qi) {
#pragma unroll
            for (int kb = 0; kb < 4; ++kb)
#pragma unroll
                for (int r = 0; r < 4; ++r) {
                    const bool masked = (kv0 + kb * 16 + c) > (q0 + 4 * g + r);
                    s[kb][r] = masked ? -INFINITY : s[kb][r] * 0.125f;
                }
        } else {
#pragma unroll
            for (int kb = 0; kb < 4; ++kb)
#pragma unroll
                for (int r = 0; r < 4; ++r) s[kb][r] *= 0.125f;
        }
#pragma unroll
        for (int kb = 0; kb < 4; ++kb)
#pragma unroll
            for (int r = 0; r < 4; ++r) mx[r] = fmaxf(mx[r], s[kb][r]);
#pragma unroll
        for (int d = 1; d < 16; d <<= 1)
#pragma unroll
            for (int r = 0; r < 4; ++r) mx[r] = fmaxf(mx[r], __shfl_xor(mx[r], d));

        float al[4], ps[4];
#pragma unroll
        for (int r = 0; r < 4; ++r) {
            const float mn = fmaxf(m_r[r], mx[r]);
            al[r] = __expf(m_r[r] - mn);
            m_r[r] = mn;
            ps[r] = 0.f;
        }
#pragma unroll
        for (int kb = 0; kb < 4; ++kb)
#pragma unroll
            for (int r = 0; r < 4; ++r) {
                const float pv = __expf(s[kb][r] - m_r[r]);
                ps[r] += pv;
                Pw[(4 * g + r) * 72 + kb * 16 + c] = f2bf(pv);
            }
#pragma unroll
        for (int d = 1; d < 16; d <<= 1)
#pragma unroll
            for (int r = 0; r < 4; ++r) ps[r] += __shfl_xor(ps[r], d);
#pragma unroll
        for (int r = 0; r < 4; ++r) l_r[r] = l_r[r] * al[r] + ps[r];
#pragma unroll
        for (int db = 0; db < 4; ++db)
#pragma unroll
            for (int r = 0; r < 4; ++r) o[db][r] *= al[r];

        // ---- PV ----
        // Pw wave-private; within-wave LDS write->read ordered by compiler.
        const bf16x8 pa0 = *(const bf16x8*)&Pw[c * 72 + g * 8];
        const bf16x8 pa1 = *(const bf16x8*)&Pw[c * 72 + 32 + g * 8];
        __builtin_amdgcn_s_setprio(1);
#pragma unroll
        for (int db = 0; db < 4; ++db) {
            o[db] = __builtin_amdgcn_mfma_f32_16x16x32_bf16(pa0, vf0[db], o[db], 0, 0, 0);
            o[db] = __builtin_amdgcn_mfma_f32_16x16x32_bf16(pa1, vf1[db], o[db], 0, 0, 0);
        }
        __builtin_amdgcn_s_setprio(0);
    }

    float invl[4];
#pragma unroll
    for (int r = 0; r < 4; ++r) invl[r] = 1.f / l_r[r];
    unsigned short* op = attn_b + ((size_t)b * TT + q0) * EE + h * HD;
#pragma unroll
    for (int db = 0; db < 4; ++db)
#pragma unroll
        for (int r = 0; r < 4; ++r)
            op[(size_t)(4 * g + r) * EE + db * 16 + c] = f2bf(o[db][r] * invl[r]);
}

extern "C" void kernel_launch(void* const* d_in, const int* in_sizes, int n_in,
                              void* d_out, int out_size, void* d_ws, size_t ws_size,
                              hipStream_t stream) {
    const float* x     = (const float*)d_in[0];
    const float* wqkv  = (const float*)d_in[1];
    const float* wproj = (const float*)d_in[2];
    float* out = (float*)d_out;

    unsigned short* ws = (unsigned short*)d_ws;
    unsigned short* q_ws    = ws;                    // [B,H,T,64]
    unsigned short* k_ws    = ws + (size_t)BTE;
    unsigned short* v_ws    = ws + 2 * (size_t)BTE;  // [B,H,64,T]
    unsigned short* xb      = ws + 3 * (size_t)BTE;  // [8192][768]
    unsigned short* attn_b  = ws + 4 * (size_t)BTE;  // [8192][768]
    unsigned short* wqkv_t  = ws + 5 * (size_t)BTE;  // [2304][768]
    unsigned short* wproj_t = wqkv_t + (size_t)2304 * 768;

    convx_kernel<<<BTE / 2048, 256, 0, stream>>>(x, xb);
    transw_kernel<<<dim3(2304 / 64, KK / 64), 256, 0, stream>>>(wqkv, wqkv_t, 2304);
    transw_kernel<<<dim3(768 / 64, KK / 64), 256, 0, stream>>>(wproj, wproj_t, 768);

    mfma_gemm_kernel<0><<<dim3(2304 / 128, 8192 / 128), 256, 0, stream>>>(
        xb, wqkv_t, q_ws, k_ws, v_ws, nullptr);
    attn_kernel<<<dim3(TT / 64, HH, BB), 256, 0, stream>>>(q_ws, k_ws, v_ws, attn_b);
    mfma_gemm_kernel<1><<<dim3(EE / 128, 8192 / 128), 256, 0, stream>>>(
        attn_b, wproj_t, nullptr, nullptr, nullptr, out);
}

// Round 5
// 291.896 us; speedup vs baseline: 1.5897x; 1.5897x over previous
//
#include <hip/hip_runtime.h>
#include <hip/hip_bf16.h>

// B=4, T=2048, E=768, H=12, hd=64.
// Round 5: staged attention again (round-3 structure), but:
//   - 128 q rows/block, 32 q rows/wave (two 16-row A-frags) -> 2x MFMA per
//     tile overhead (barriers, staging, K-frag reads)
//   - T14 async-stage: next tile's global loads issued after barrier-2,
//     latency hides under current tile's compute
//   p1: xb = bf16(x); p2/p3: transposed bf16 weights
//   k1: qkv MFMA GEMM -> bf16 q,k [B,H,T,64], v^T [B,H,64,T]
//   k2: MFMA flash attention -> bf16 [B,T,E]
//   k3: proj MFMA GEMM -> f32 out

#define BB 4
#define TT 2048
#define EE 768
#define HH 12
#define HD 64
#define KK 768
#define BTE (BB*TT*EE)  // 6291456

typedef __attribute__((ext_vector_type(8))) short bf16x8;
typedef __attribute__((ext_vector_type(4))) float f32x4;

static __device__ __forceinline__ unsigned short f2bf(float f) {
    unsigned u = __builtin_bit_cast(unsigned, f);
    u += 0x7fffu + ((u >> 16) & 1u);   // RNE
    return (unsigned short)(u >> 16);
}

// ---------------------------------------------------------------------------
__global__ __launch_bounds__(256)
void convx_kernel(const float* __restrict__ x, unsigned short* __restrict__ xb) {
    const size_t i = ((size_t)blockIdx.x * 256 + threadIdx.x) * 8;
    float4 a = *(const float4*)&x[i];
    float4 b = *(const float4*)&x[i + 4];
    ushort4 lo, hi;
    lo.x = f2bf(a.x); lo.y = f2bf(a.y); lo.z = f2bf(a.z); lo.w = f2bf(a.w);
    hi.x = f2bf(b.x); hi.y = f2bf(b.y); hi.z = f2bf(b.z); hi.w = f2bf(b.w);
    *(ushort4*)&xb[i] = lo;
    *(ushort4*)&xb[i + 4] = hi;
}

// ---------------------------------------------------------------------------
__global__ __launch_bounds__(256)
void transw_kernel(const float* __restrict__ W, unsigned short* __restrict__ Wt, int N) {
    __shared__ unsigned short Ts[64][72];
    const int n0 = blockIdx.x * 64;
    const int k0 = blockIdx.y * 64;
    const int tid = threadIdx.x;
    {
        const int r = tid >> 4;
        const int c4 = (tid & 15) << 2;
#pragma unroll
        for (int i = 0; i < 4; ++i) {
            const int k = r + i * 16;
            float4 w4 = *(const float4*)&W[(size_t)(k0 + k) * N + n0 + c4];
            Ts[k][c4 + 0] = f2bf(w4.x); Ts[k][c4 + 1] = f2bf(w4.y);
            Ts[k][c4 + 2] = f2bf(w4.z); Ts[k][c4 + 3] = f2bf(w4.w);
        }
    }
    __syncthreads();
#pragma unroll
    for (int i = 0; i < 2; ++i) {
        const int idx = tid + i * 256;
        const int n = idx >> 3;
        const int ch = idx & 7;
        ushort4 p0, p1;
        p0.x = Ts[ch * 8 + 0][n]; p0.y = Ts[ch * 8 + 1][n];
        p0.z = Ts[ch * 8 + 2][n]; p0.w = Ts[ch * 8 + 3][n];
        p1.x = Ts[ch * 8 + 4][n]; p1.y = Ts[ch * 8 + 5][n];
        p1.z = Ts[ch * 8 + 6][n]; p1.w = Ts[ch * 8 + 7][n];
        *(ushort4*)&Wt[(size_t)(n0 + n) * KK + k0 + ch * 8] = p0;
        *(ushort4*)&Wt[(size_t)(n0 + n) * KK + k0 + ch * 8 + 4] = p1;
    }
}

// ---------------------------------------------------------------------------
// bf16 MFMA GEMM (unchanged from round 3)
// ---------------------------------------------------------------------------
template<int MODE>
__global__ __launch_bounds__(256)
void mfma_gemm_kernel(const unsigned short* __restrict__ A,
                      const unsigned short* __restrict__ Wt,
                      unsigned short* __restrict__ q_ws,
                      unsigned short* __restrict__ k_ws,
                      unsigned short* __restrict__ v_ws,
                      float* __restrict__ outf) {
    __shared__ __align__(16) unsigned short As[128 * 40];
    __shared__ __align__(16) unsigned short Bs[128 * 40];
    const int bx = blockIdx.x;
    const int by = blockIdx.y;
    const int tid = threadIdx.x;
    const int w = tid >> 6, lane = tid & 63;
    const int c = lane & 15, g = lane >> 4;
    const int wr = w >> 1, wc = w & 1;
    const int m0 = by * 128, n0 = bx * 128;

    const int r0 = tid >> 2;
    const int ch = tid & 3;

    const unsigned short* Ap = A  + (size_t)m0 * KK;
    const unsigned short* Bp = Wt + (size_t)n0 * KK;

    f32x4 acc[4][4] = {};

    for (int kt = 0; kt < KK / 32; ++kt) {
        const int k0 = kt * 32;
        const uint4 a0 = *(const uint4*)&Ap[(size_t)r0 * KK + k0 + ch * 8];
        const uint4 a1 = *(const uint4*)&Ap[(size_t)(r0 + 64) * KK + k0 + ch * 8];
        const uint4 b0 = *(const uint4*)&Bp[(size_t)r0 * KK + k0 + ch * 8];
        const uint4 b1 = *(const uint4*)&Bp[(size_t)(r0 + 64) * KK + k0 + ch * 8];
        __syncthreads();
        *(uint4*)&As[r0 * 40 + ch * 8]        = a0;
        *(uint4*)&As[(r0 + 64) * 40 + ch * 8] = a1;
        *(uint4*)&Bs[r0 * 40 + ch * 8]        = b0;
        *(uint4*)&Bs[(r0 + 64) * 40 + ch * 8] = b1;
        __syncthreads();

        bf16x8 af[4], bfr[4];
#pragma unroll
        for (int m = 0; m < 4; ++m)
            af[m] = *(const bf16x8*)&As[(wr * 64 + m * 16 + c) * 40 + g * 8];
#pragma unroll
        for (int n = 0; n < 4; ++n)
            bfr[n] = *(const bf16x8*)&Bs[(wc * 64 + n * 16 + c) * 40 + g * 8];
#pragma unroll
        for (int m = 0; m < 4; ++m)
#pragma unroll
            for (int n = 0; n < 4; ++n)
                acc[m][n] = __builtin_amdgcn_mfma_f32_16x16x32_bf16(af[m], bfr[n], acc[m][n], 0, 0, 0);
    }

    if (MODE == 0) {
        const int which = n0 / EE;
        const int h = (n0 % EE) / HD + wc;
        const int b = m0 / TT;
        const int tb = (m0 % TT) + wr * 64;
        if (which < 2) {
            unsigned short* dst = (which == 0) ? q_ws : k_ws;
            unsigned short* base = dst + (((size_t)b * HH + h) * TT) * HD;
#pragma unroll
            for (int m = 0; m < 4; ++m)
#pragma unroll
                for (int n = 0; n < 4; ++n)
#pragma unroll
                    for (int j = 0; j < 4; ++j)
                        base[(size_t)(tb + m * 16 + 4 * g + j) * HD + n * 16 + c] =
                            f2bf(acc[m][n][j]);
        } else {
            unsigned short* base = v_ws + (((size_t)b * HH + h) * HD) * TT;
#pragma unroll
            for (int m = 0; m < 4; ++m)
#pragma unroll
                for (int n = 0; n < 4; ++n)
#pragma unroll
                    for (int j = 0; j < 4; ++j)
                        base[(size_t)(n * 16 + c) * TT + tb + m * 16 + 4 * g + j] =
                            f2bf(acc[m][n][j]);
        }
    } else {
#pragma unroll
        for (int m = 0; m < 4; ++m)
#pragma unroll
            for (int n = 0; n < 4; ++n)
#pragma unroll
                for (int j = 0; j < 4; ++j)
                    outf[(size_t)(m0 + wr * 64 + m * 16 + 4 * g + j) * EE
                         + n0 + wc * 64 + n * 16 + c] = acc[m][n][j];
    }
}

// ---------------------------------------------------------------------------
// MFMA flash attention. Block = (b, h, 128 q rows), 4 waves, wave w owns
// rows [qi*128 + w*32, +32) as two 16-row A-frags. K/V tiles of 64 staged
// to padded LDS; next tile's loads issued before compute (T14).
// ---------------------------------------------------------------------------
__global__ __launch_bounds__(256)
void attn_kernel(const unsigned short* __restrict__ q,
                 const unsigned short* __restrict__ k,
                 const unsigned short* __restrict__ vt,
                 unsigned short* __restrict__ attn_b) {
    __shared__ __align__(16) unsigned short Ks[64 * 72];       // [key][d]
    __shared__ __align__(16) unsigned short Vt[64 * 72];       // [d][key]
    __shared__ __align__(16) unsigned short Pb[4 * 32 * 72];   // per-wave P

    const int qi = (TT / 128 - 1) - blockIdx.x;   // heavy blocks first
    const int h = blockIdx.y, b = blockIdx.z;
    const int tid = threadIdx.x;
    const int w = tid >> 6;
    const int lane = tid & 63;
    const int c = lane & 15;
    const int g = lane >> 4;

    const size_t head_off = (size_t)(b * HH + h) * TT * HD;
    const unsigned short* qp = q + head_off;
    const unsigned short* kp = k + head_off;
    const unsigned short* vp = vt + head_off;   // [64][T]

    const int q0w = qi * 128 + w * 32;

    bf16x8 qa0[2], qa1[2];
#pragma unroll
    for (int f = 0; f < 2; ++f) {
        qa0[f] = *(const bf16x8*)&qp[(size_t)(q0w + f * 16 + c) * HD + g * 8];
        qa1[f] = *(const bf16x8*)&qp[(size_t)(q0w + f * 16 + c) * HD + 32 + g * 8];
    }

    unsigned short* Pw = &Pb[w * 32 * 72];

    f32x4 o[2][4] = {};
    float m_r[2][4], l_r[2][4];
#pragma unroll
    for (int f = 0; f < 2; ++f)
#pragma unroll
        for (int r = 0; r < 4; ++r) { m_r[f][r] = -INFINITY; l_r[f][r] = 0.f; }

    const int skey = tid >> 2;       // 0..63
    const int sc = tid & 3;

    const int ktiles = 2 * qi + 2;

    // prologue: tile 0 loads
    uint4 kA = *(const uint4*)&kp[(size_t)skey * HD + sc * 16];
    uint4 kB = *(const uint4*)&kp[(size_t)skey * HD + sc * 16 + 8];
    uint4 vA = *(const uint4*)&vp[(size_t)skey * TT + sc * 16];
    uint4 vB = *(const uint4*)&vp[(size_t)skey * TT + sc * 16 + 8];

    for (int kt = 0; kt < ktiles; ++kt) {
        const int kv0 = kt * 64;
        __syncthreads();   // prev tile's LDS reads done
        *(uint4*)&Ks[skey * 72 + sc * 16]     = kA;
        *(uint4*)&Ks[skey * 72 + sc * 16 + 8] = kB;
        *(uint4*)&Vt[skey * 72 + sc * 16]     = vA;
        *(uint4*)&Vt[skey * 72 + sc * 16 + 8] = vB;
        __syncthreads();

        // T14: issue next tile's loads now; latency hides under compute
        if (kt + 1 < ktiles) {
            const int nv0 = kv0 + 64;
            kA = *(const uint4*)&kp[(size_t)(nv0 + skey) * HD + sc * 16];
            kB = *(const uint4*)&kp[(size_t)(nv0 + skey) * HD + sc * 16 + 8];
            vA = *(const uint4*)&vp[(size_t)skey * TT + nv0 + sc * 16];
            vB = *(const uint4*)&vp[(size_t)skey * TT + nv0 + sc * 16 + 8];
        }

        if (kv0 > q0w + 31) continue;   // beyond this wave's rows (barriers already done)

        // ---- QK^T: S[2][16 q][64 key] ----
        f32x4 s[2][4];
#pragma unroll
        for (int kb = 0; kb < 4; ++kb) {
            const bf16x8 kb0 = *(const bf16x8*)&Ks[(kb * 16 + c) * 72 + g * 8];
            const bf16x8 kb1 = *(const bf16x8*)&Ks[(kb * 16 + c) * 72 + 32 + g * 8];
#pragma unroll
            for (int f = 0; f < 2; ++f) {
                f32x4 z = {0.f, 0.f, 0.f, 0.f};
                z = __builtin_amdgcn_mfma_f32_16x16x32_bf16(qa0[f], kb0, z, 0, 0, 0);
                s[f][kb] = __builtin_amdgcn_mfma_f32_16x16x32_bf16(qa1[f], kb1, z, 0, 0, 0);
            }
        }

        // ---- online softmax (row q = f*16 + 4g+r, col key = kb*16+c) ----
        if (kv0 + 63 > q0w) {
#pragma unroll
            for (int f = 0; f < 2; ++f)
#pragma unroll
                for (int kb = 0; kb < 4; ++kb)
#pragma unroll
                    for (int r = 0; r < 4; ++r) {
                        const bool masked = (kv0 + kb * 16 + c) > (q0w + f * 16 + 4 * g + r);
                        s[f][kb][r] = masked ? -INFINITY : s[f][kb][r] * 0.125f;
                    }
        } else {
#pragma unroll
            for (int f = 0; f < 2; ++f)
#pragma unroll
                for (int kb = 0; kb < 4; ++kb)
#pragma unroll
                    for (int r = 0; r < 4; ++r) s[f][kb][r] *= 0.125f;
        }

        float mx[2][4];
#pragma unroll
        for (int f = 0; f < 2; ++f)
#pragma unroll
            for (int r = 0; r < 4; ++r) mx[f][r] = -INFINITY;
#pragma unroll
        for (int f = 0; f < 2; ++f)
#pragma unroll
            for (int kb = 0; kb < 4; ++kb)
#pragma unroll
                for (int r = 0; r < 4; ++r) mx[f][r] = fmaxf(mx[f][r], s[f][kb][r]);
#pragma unroll
        for (int d = 1; d < 16; d <<= 1)
#pragma unroll
            for (int f = 0; f < 2; ++f)
#pragma unroll
                for (int r = 0; r < 4; ++r) mx[f][r] = fmaxf(mx[f][r], __shfl_xor(mx[f][r], d));

        float al[2][4], ps[2][4];
#pragma unroll
        for (int f = 0; f < 2; ++f)
#pragma unroll
            for (int r = 0; r < 4; ++r) {
                const float mn = fmaxf(m_r[f][r], mx[f][r]);
                al[f][r] = __expf(m_r[f][r] - mn);
                m_r[f][r] = mn;
                ps[f][r] = 0.f;
            }
#pragma unroll
        for (int f = 0; f < 2; ++f)
#pragma unroll
            for (int kb = 0; kb < 4; ++kb)
#pragma unroll
                for (int r = 0; r < 4; ++r) {
                    const float pv = __expf(s[f][kb][r] - m_r[f][r]);
                    ps[f][r] += pv;
                    Pw[(f * 16 + 4 * g + r) * 72 + kb * 16 + c] = f2bf(pv);
                }
#pragma unroll
        for (int d = 1; d < 16; d <<= 1)
#pragma unroll
            for (int f = 0; f < 2; ++f)
#pragma unroll
                for (int r = 0; r < 4; ++r) ps[f][r] += __shfl_xor(ps[f][r], d);
#pragma unroll
        for (int f = 0; f < 2; ++f)
#pragma unroll
            for (int r = 0; r < 4; ++r) l_r[f][r] = l_r[f][r] * al[f][r] + ps[f][r];
#pragma unroll
        for (int f = 0; f < 2; ++f)
#pragma unroll
            for (int db = 0; db < 4; ++db)
#pragma unroll
                for (int r = 0; r < 4; ++r) o[f][db][r] *= al[f][r];

        // ---- PV (Pw wave-private; within-wave LDS ordering by compiler) ----
        bf16x8 pa0[2], pa1[2];
#pragma unroll
        for (int f = 0; f < 2; ++f) {
            pa0[f] = *(const bf16x8*)&Pw[(f * 16 + c) * 72 + g * 8];
            pa1[f] = *(const bf16x8*)&Pw[(f * 16 + c) * 72 + 32 + g * 8];
        }
#pragma unroll
        for (int db = 0; db < 4; ++db) {
            const bf16x8 vb0 = *(const bf16x8*)&Vt[(db * 16 + c) * 72 + g * 8];
            const bf16x8 vb1 = *(const bf16x8*)&Vt[(db * 16 + c) * 72 + 32 + g * 8];
#pragma unroll
            for (int f = 0; f < 2; ++f) {
                o[f][db] = __builtin_amdgcn_mfma_f32_16x16x32_bf16(pa0[f], vb0, o[f][db], 0, 0, 0);
                o[f][db] = __builtin_amdgcn_mfma_f32_16x16x32_bf16(pa1[f], vb1, o[f][db], 0, 0, 0);
            }
        }
    }

    unsigned short* op = attn_b + ((size_t)b * TT + q0w) * EE + h * HD;
#pragma unroll
    for (int f = 0; f < 2; ++f) {
        float invl[4];
#pragma unroll
        for (int r = 0; r < 4; ++r) invl[r] = 1.f / l_r[f][r];
#pragma unroll
        for (int db = 0; db < 4; ++db)
#pragma unroll
            for (int r = 0; r < 4; ++r)
                op[(size_t)(f * 16 + 4 * g + r) * EE + db * 16 + c] =
                    f2bf(o[f][db][r] * invl[r]);
    }
}

extern "C" void kernel_launch(void* const* d_in, const int* in_sizes, int n_in,
                              void* d_out, int out_size, void* d_ws, size_t ws_size,
                              hipStream_t stream) {
    const float* x     = (const float*)d_in[0];
    const float* wqkv  = (const float*)d_in[1];
    const float* wproj = (const float*)d_in[2];
    float* out = (float*)d_out;

    unsigned short* ws = (unsigned short*)d_ws;
    unsigned short* q_ws    = ws;                    // [B,H,T,64]
    unsigned short* k_ws    = ws + (size_t)BTE;
    unsigned short* v_ws    = ws + 2 * (size_t)BTE;  // [B,H,64,T]
    unsigned short* xb      = ws + 3 * (size_t)BTE;  // [8192][768]
    unsigned short* attn_b  = ws + 4 * (size_t)BTE;  // [8192][768]
    unsigned short* wqkv_t  = ws + 5 * (size_t)BTE;  // [2304][768]
    unsigned short* wproj_t = wqkv_t + (size_t)2304 * 768;

    convx_kernel<<<BTE / 2048, 256, 0, stream>>>(x, xb);
    transw_kernel<<<dim3(2304 / 64, KK / 64), 256, 0, stream>>>(wqkv, wqkv_t, 2304);
    transw_kernel<<<dim3(768 / 64, KK / 64), 256, 0, stream>>>(wproj, wproj_t, 768);

    mfma_gemm_kernel<0><<<dim3(2304 / 128, 8192 / 128), 256, 0, stream>>>(
        xb, wqkv_t, q_ws, k_ws, v_ws, nullptr);
    attn_kernel<<<dim3(TT / 128, HH, BB), 256, 0, stream>>>(q_ws, k_ws, v_ws, attn_b);
    mfma_gemm_kernel<1><<<dim3(EE / 128, 8192 / 128), 256, 0, stream>>>(
        attn_b, wproj_t, nullptr, nullptr, nullptr, out);
}

// Round 6
// 268.140 us; speedup vs baseline: 1.7306x; 1.0886x over previous
//
#include <hip/hip_runtime.h>
#include <hip/hip_bf16.h>

// B=4, T=2048, E=768, H=12, hd=64.
// Round 6: swapped-QK^T attention (T12): row softmax in-lane (2 shfl not 16),
// P in registers via cvt_pk + shfl (no LDS P buffer), double-buffered K/V
// with ONE barrier per tile, Q pre-scaled by 0.125*log2e -> exp2 domain.

#define BB 4
#define TT 2048
#define EE 768
#define HH 12
#define HD 64
#define KK 768
#define BTE (BB*TT*EE)  // 6291456

typedef __attribute__((ext_vector_type(8))) short bf16x8;
typedef __attribute__((ext_vector_type(4))) float f32x4;
typedef __attribute__((ext_vector_type(4))) int i32x4;

#define QSC 0.18033688011112042f   // 0.125 * log2(e)

static __device__ __forceinline__ unsigned short f2bf(float f) {
    unsigned u = __builtin_bit_cast(unsigned, f);
    u += 0x7fffu + ((u >> 16) & 1u);   // RNE
    return (unsigned short)(u >> 16);
}

static __device__ __forceinline__ unsigned cvt_pk_bf16(float lo, float hi) {
    unsigned r;
    asm("v_cvt_pk_bf16_f32 %0, %1, %2" : "=v"(r) : "v"(lo), "v"(hi));
    return r;
}

// ---------------------------------------------------------------------------
__global__ __launch_bounds__(256)
void convx_kernel(const float* __restrict__ x, unsigned short* __restrict__ xb) {
    const size_t i = ((size_t)blockIdx.x * 256 + threadIdx.x) * 8;
    float4 a = *(const float4*)&x[i];
    float4 b = *(const float4*)&x[i + 4];
    ushort4 lo, hi;
    lo.x = f2bf(a.x); lo.y = f2bf(a.y); lo.z = f2bf(a.z); lo.w = f2bf(a.w);
    hi.x = f2bf(b.x); hi.y = f2bf(b.y); hi.z = f2bf(b.z); hi.w = f2bf(b.w);
    *(ushort4*)&xb[i] = lo;
    *(ushort4*)&xb[i + 4] = hi;
}

// ---------------------------------------------------------------------------
__global__ __launch_bounds__(256)
void transw_kernel(const float* __restrict__ W, unsigned short* __restrict__ Wt, int N) {
    __shared__ unsigned short Ts[64][72];
    const int n0 = blockIdx.x * 64;
    const int k0 = blockIdx.y * 64;
    const int tid = threadIdx.x;
    {
        const int r = tid >> 4;
        const int c4 = (tid & 15) << 2;
#pragma unroll
        for (int i = 0; i < 4; ++i) {
            const int k = r + i * 16;
            float4 w4 = *(const float4*)&W[(size_t)(k0 + k) * N + n0 + c4];
            Ts[k][c4 + 0] = f2bf(w4.x); Ts[k][c4 + 1] = f2bf(w4.y);
            Ts[k][c4 + 2] = f2bf(w4.z); Ts[k][c4 + 3] = f2bf(w4.w);
        }
    }
    __syncthreads();
#pragma unroll
    for (int i = 0; i < 2; ++i) {
        const int idx = tid + i * 256;
        const int n = idx >> 3;
        const int ch = idx & 7;
        ushort4 p0, p1;
        p0.x = Ts[ch * 8 + 0][n]; p0.y = Ts[ch * 8 + 1][n];
        p0.z = Ts[ch * 8 + 2][n]; p0.w = Ts[ch * 8 + 3][n];
        p1.x = Ts[ch * 8 + 4][n]; p1.y = Ts[ch * 8 + 5][n];
        p1.z = Ts[ch * 8 + 6][n]; p1.w = Ts[ch * 8 + 7][n];
        *(ushort4*)&Wt[(size_t)(n0 + n) * KK + k0 + ch * 8] = p0;
        *(ushort4*)&Wt[(size_t)(n0 + n) * KK + k0 + ch * 8 + 4] = p1;
    }
}

// ---------------------------------------------------------------------------
// bf16 MFMA GEMM (as round 5; q output pre-scaled by QSC)
// ---------------------------------------------------------------------------
template<int MODE>
__global__ __launch_bounds__(256)
void mfma_gemm_kernel(const unsigned short* __restrict__ A,
                      const unsigned short* __restrict__ Wt,
                      unsigned short* __restrict__ q_ws,
                      unsigned short* __restrict__ k_ws,
                      unsigned short* __restrict__ v_ws,
                      float* __restrict__ outf) {
    __shared__ __align__(16) unsigned short As[128 * 40];
    __shared__ __align__(16) unsigned short Bs[128 * 40];
    const int bx = blockIdx.x;
    const int by = blockIdx.y;
    const int tid = threadIdx.x;
    const int w = tid >> 6, lane = tid & 63;
    const int c = lane & 15, g = lane >> 4;
    const int wr = w >> 1, wc = w & 1;
    const int m0 = by * 128, n0 = bx * 128;

    const int r0 = tid >> 2;
    const int ch = tid & 3;

    const unsigned short* Ap = A  + (size_t)m0 * KK;
    const unsigned short* Bp = Wt + (size_t)n0 * KK;

    f32x4 acc[4][4] = {};

    for (int kt = 0; kt < KK / 32; ++kt) {
        const int k0 = kt * 32;
        const uint4 a0 = *(const uint4*)&Ap[(size_t)r0 * KK + k0 + ch * 8];
        const uint4 a1 = *(const uint4*)&Ap[(size_t)(r0 + 64) * KK + k0 + ch * 8];
        const uint4 b0 = *(const uint4*)&Bp[(size_t)r0 * KK + k0 + ch * 8];
        const uint4 b1 = *(const uint4*)&Bp[(size_t)(r0 + 64) * KK + k0 + ch * 8];
        __syncthreads();
        *(uint4*)&As[r0 * 40 + ch * 8]        = a0;
        *(uint4*)&As[(r0 + 64) * 40 + ch * 8] = a1;
        *(uint4*)&Bs[r0 * 40 + ch * 8]        = b0;
        *(uint4*)&Bs[(r0 + 64) * 40 + ch * 8] = b1;
        __syncthreads();

        bf16x8 af[4], bfr[4];
#pragma unroll
        for (int m = 0; m < 4; ++m)
            af[m] = *(const bf16x8*)&As[(wr * 64 + m * 16 + c) * 40 + g * 8];
#pragma unroll
        for (int n = 0; n < 4; ++n)
            bfr[n] = *(const bf16x8*)&Bs[(wc * 64 + n * 16 + c) * 40 + g * 8];
#pragma unroll
        for (int m = 0; m < 4; ++m)
#pragma unroll
            for (int n = 0; n < 4; ++n)
                acc[m][n] = __builtin_amdgcn_mfma_f32_16x16x32_bf16(af[m], bfr[n], acc[m][n], 0, 0, 0);
    }

    if (MODE == 0) {
        const int which = n0 / EE;
        const int h = (n0 % EE) / HD + wc;
        const int b = m0 / TT;
        const int tb = (m0 % TT) + wr * 64;
        if (which < 2) {
            const float sc_ = (which == 0) ? QSC : 1.0f;   // pre-scale q
            unsigned short* dst = (which == 0) ? q_ws : k_ws;
            unsigned short* base = dst + (((size_t)b * HH + h) * TT) * HD;
#pragma unroll
            for (int m = 0; m < 4; ++m)
#pragma unroll
                for (int n = 0; n < 4; ++n)
#pragma unroll
                    for (int j = 0; j < 4; ++j)
                        base[(size_t)(tb + m * 16 + 4 * g + j) * HD + n * 16 + c] =
                            f2bf(acc[m][n][j] * sc_);
        } else {
            unsigned short* base = v_ws + (((size_t)b * HH + h) * HD) * TT;
#pragma unroll
            for (int m = 0; m < 4; ++m)
#pragma unroll
                for (int n = 0; n < 4; ++n)
#pragma unroll
                    for (int j = 0; j < 4; ++j)
                        base[(size_t)(n * 16 + c) * TT + tb + m * 16 + 4 * g + j] =
                            f2bf(acc[m][n][j]);
        }
    } else {
#pragma unroll
        for (int m = 0; m < 4; ++m)
#pragma unroll
            for (int n = 0; n < 4; ++n)
#pragma unroll
                for (int j = 0; j < 4; ++j)
                    outf[(size_t)(m0 + wr * 64 + m * 16 + 4 * g + j) * EE
                         + n0 + wc * 64 + n * 16 + c] = acc[m][n][j];
    }
}

// ---------------------------------------------------------------------------
// Swapped-QK^T MFMA flash attention.
// Block = (b, h, 128 q rows), 4 waves x 32 rows (two 16-row frags).
// s = mfma(Kfrag, Qfrag): lane (c,g) reg r holds S[key=kb*16+4g+r][q=q0f+c]
// -> softmax per q is in-lane (15 VALU) + 2 shfl_xor. P packed via
// v_cvt_pk_bf16_f32, moved to PV A-frag layout with 16 shfl + 8 selects.
// K/V double-buffered in LDS, ONE barrier per tile; next-tile global loads
// issued before compute (T14).
// ---------------------------------------------------------------------------
__global__ __launch_bounds__(256, 4)
void attn_kernel(const unsigned short* __restrict__ q,
                 const unsigned short* __restrict__ k,
                 const unsigned short* __restrict__ vt,
                 unsigned short* __restrict__ attn_b) {
    __shared__ __align__(16) unsigned short Ks[2][64 * 72];   // [key][d]
    __shared__ __align__(16) unsigned short Vt[2][64 * 72];   // [d][key]

    const int qi = (TT / 128 - 1) - blockIdx.x;   // heavy blocks first
    const int h = blockIdx.y, b = blockIdx.z;
    const int tid = threadIdx.x;
    const int w = tid >> 6;
    const int lane = tid & 63;
    const int c = lane & 15;
    const int g = lane >> 4;

    const size_t head_off = (size_t)(b * HH + h) * TT * HD;
    const unsigned short* qp = q + head_off;
    const unsigned short* kp = k + head_off;
    const unsigned short* vp = vt + head_off;   // [64][T]

    const int q0w = qi * 128 + w * 32;

    bf16x8 qa0[2], qa1[2];
#pragma unroll
    for (int f = 0; f < 2; ++f) {
        qa0[f] = *(const bf16x8*)&qp[(size_t)(q0w + f * 16 + c) * HD + g * 8];
        qa1[f] = *(const bf16x8*)&qp[(size_t)(q0w + f * 16 + c) * HD + 32 + g * 8];
    }

    f32x4 o[2][4] = {};
    float m_r[2] = {-INFINITY, -INFINITY};
    float l_r[2] = {0.f, 0.f};

    const int skey = tid >> 2;       // 0..63
    const int sc = tid & 3;

    const int ktiles = 2 * qi + 2;

    // prologue: tile 0 -> buf 0
    uint4 kA = *(const uint4*)&kp[(size_t)skey * HD + sc * 16];
    uint4 kB = *(const uint4*)&kp[(size_t)skey * HD + sc * 16 + 8];
    uint4 vA = *(const uint4*)&vp[(size_t)skey * TT + sc * 16];
    uint4 vB = *(const uint4*)&vp[(size_t)skey * TT + sc * 16 + 8];
    *(uint4*)&Ks[0][skey * 72 + sc * 16]     = kA;
    *(uint4*)&Ks[0][skey * 72 + sc * 16 + 8] = kB;
    *(uint4*)&Vt[0][skey * 72 + sc * 16]     = vA;
    *(uint4*)&Vt[0][skey * 72 + sc * 16 + 8] = vB;
    __syncthreads();
    int p = 0;

    for (int kt = 0; kt < ktiles; ++kt) {
        const int kv0 = kt * 64;
        const bool last = (kt + 1 == ktiles);
        if (!last) {   // issue next tile's loads now (latency under compute)
            const int nv0 = kv0 + 64;
            kA = *(const uint4*)&kp[(size_t)(nv0 + skey) * HD + sc * 16];
            kB = *(const uint4*)&kp[(size_t)(nv0 + skey) * HD + sc * 16 + 8];
            vA = *(const uint4*)&vp[(size_t)skey * TT + nv0 + sc * 16];
            vB = *(const uint4*)&vp[(size_t)skey * TT + nv0 + sc * 16 + 8];
        }

        if (kv0 <= q0w + 31) {
            const unsigned short* Kp = Ks[p];
            const unsigned short* Vp = Vt[p];

            // ---- QK^T (swapped): s[f][kb] reg r = S[key=kb*16+4g+r][q=q0f+c]
            f32x4 s[2][4];
            __builtin_amdgcn_s_setprio(1);
#pragma unroll
            for (int kb = 0; kb < 4; ++kb) {
                const bf16x8 k0v = *(const bf16x8*)&Kp[(kb * 16 + c) * 72 + g * 8];
                const bf16x8 k1v = *(const bf16x8*)&Kp[(kb * 16 + c) * 72 + 32 + g * 8];
#pragma unroll
                for (int f = 0; f < 2; ++f) {
                    f32x4 z = {0.f, 0.f, 0.f, 0.f};
                    z = __builtin_amdgcn_mfma_f32_16x16x32_bf16(k0v, qa0[f], z, 0, 0, 0);
                    s[f][kb] = __builtin_amdgcn_mfma_f32_16x16x32_bf16(k1v, qa1[f], z, 0, 0, 0);
                }
            }
            __builtin_amdgcn_s_setprio(0);

            int paw[2][8];
            bool fact[2];
#pragma unroll
            for (int f = 0; f < 2; ++f) {
                const int q0f = q0w + f * 16;
                fact[f] = (kv0 <= q0f + 15);
                if (!fact[f]) continue;   // frag fully masked this tile

                if (kv0 + 63 > q0f) {     // diagonal tile: causal mask
                    const int rhs = q0f + c - kv0;   // key_local > rhs -> mask
#pragma unroll
                    for (int kb = 0; kb < 4; ++kb)
#pragma unroll
                        for (int r = 0; r < 4; ++r)
                            if (kb * 16 + 4 * g + r > rhs) s[f][kb][r] = -INFINITY;
                }

                // row max: in-lane tree + 2 shfl (q = c, uniform over g after)
                float mx;
                {
                    f32x4 t0;
#pragma unroll
                    for (int e = 0; e < 4; ++e)
                        t0[e] = fmaxf(fmaxf(s[f][0][e], s[f][1][e]),
                                      fmaxf(s[f][2][e], s[f][3][e]));
                    mx = fmaxf(fmaxf(t0[0], t0[1]), fmaxf(t0[2], t0[3]));
                }
                mx = fmaxf(mx, __shfl_xor(mx, 16));
                mx = fmaxf(mx, __shfl_xor(mx, 32));

                const bool grow = (__all(mx <= m_r[f]) == 0);
                float alpha = 1.f;
                if (grow) {   // exact: only rescale when the max moved
                    const float mn = fmaxf(m_r[f], mx);
                    alpha = exp2f(m_r[f] - mn);
                    m_r[f] = mn;
                }

                // p = 2^(s - m); sum in-lane + 2 shfl
                float px[4][4];
#pragma unroll
                for (int kb = 0; kb < 4; ++kb)
#pragma unroll
                    for (int r = 0; r < 4; ++r)
                        px[kb][r] = exp2f(s[f][kb][r] - m_r[f]);
                float psum;
                {
                    f32x4 a0;
#pragma unroll
                    for (int e = 0; e < 4; ++e)
                        a0[e] = (px[0][e] + px[1][e]) + (px[2][e] + px[3][e]);
                    psum = (a0[0] + a0[1]) + (a0[2] + a0[3]);
                }
                psum += __shfl_xor(psum, 16);
                psum += __shfl_xor(psum, 32);
                l_r[f] = (grow ? l_r[f] * alpha : l_r[f]) + psum;

                if (grow) {   // o-rescale needs alpha in o-layout (q=4g+r)
                    float alo[4];
#pragma unroll
                    for (int r = 0; r < 4; ++r) alo[r] = __shfl(alpha, 20 * g + r);
#pragma unroll
                    for (int db = 0; db < 4; ++db)
#pragma unroll
                        for (int r = 0; r < 4; ++r) o[f][db][r] *= alo[r];
                }

                // pack to bf16 pairs and redistribute to PV A-frag layout:
                // pa0 word w: pk[g>>1][w&1] from lane (c, 2(g&1) + (w>>1))
                unsigned pk[4][2];
#pragma unroll
                for (int kb = 0; kb < 4; ++kb) {
                    pk[kb][0] = cvt_pk_bf16(px[kb][0], px[kb][1]);
                    pk[kb][1] = cvt_pk_bf16(px[kb][2], px[kb][3]);
                }
                const int sA = c + 32 * (g & 1);
                const int sB = sA + 16;
                const bool hi = (g >= 2);
                unsigned a_, b_;
                a_ = __shfl(pk[0][0], sA); b_ = __shfl(pk[1][0], sA); paw[f][0] = (int)(hi ? b_ : a_);
                a_ = __shfl(pk[0][1], sA); b_ = __shfl(pk[1][1], sA); paw[f][1] = (int)(hi ? b_ : a_);
                a_ = __shfl(pk[0][0], sB); b_ = __shfl(pk[1][0], sB); paw[f][2] = (int)(hi ? b_ : a_);
                a_ = __shfl(pk[0][1], sB); b_ = __shfl(pk[1][1], sB); paw[f][3] = (int)(hi ? b_ : a_);
                a_ = __shfl(pk[2][0], sA); b_ = __shfl(pk[3][0], sA); paw[f][4] = (int)(hi ? b_ : a_);
                a_ = __shfl(pk[2][1], sA); b_ = __shfl(pk[3][1], sA); paw[f][5] = (int)(hi ? b_ : a_);
                a_ = __shfl(pk[2][0], sB); b_ = __shfl(pk[3][0], sB); paw[f][6] = (int)(hi ? b_ : a_);
                a_ = __shfl(pk[2][1], sB); b_ = __shfl(pk[3][1], sB); paw[f][7] = (int)(hi ? b_ : a_);
            }

            // ---- PV: o[f][db] reg r = O[q=q0f+4g+r][d=db*16+c] ----
            __builtin_amdgcn_s_setprio(1);
#pragma unroll
            for (int db = 0; db < 4; ++db) {
                const bf16x8 vb0 = *(const bf16x8*)&Vp[(db * 16 + c) * 72 + g * 8];
                const bf16x8 vb1 = *(const bf16x8*)&Vp[(db * 16 + c) * 72 + 32 + g * 8];
#pragma unroll
                for (int f = 0; f < 2; ++f) {
                    if (!fact[f]) continue;
                    i32x4 w0 = {paw[f][0], paw[f][1], paw[f][2], paw[f][3]};
                    i32x4 w1 = {paw[f][4], paw[f][5], paw[f][6], paw[f][7]};
                    o[f][db] = __builtin_amdgcn_mfma_f32_16x16x32_bf16(
                        __builtin_bit_cast(bf16x8, w0), vb0, o[f][db], 0, 0, 0);
                    o[f][db] = __builtin_amdgcn_mfma_f32_16x16x32_bf16(
                        __builtin_bit_cast(bf16x8, w1), vb1, o[f][db], 0, 0, 0);
                }
            }
            __builtin_amdgcn_s_setprio(0);
        }

        if (!last) {   // write next tile into the other buffer
            const int pn = p ^ 1;
            *(uint4*)&Ks[pn][skey * 72 + sc * 16]     = kA;
            *(uint4*)&Ks[pn][skey * 72 + sc * 16 + 8] = kB;
            *(uint4*)&Vt[pn][skey * 72 + sc * 16]     = vA;
            *(uint4*)&Vt[pn][skey * 72 + sc * 16 + 8] = vB;
        }
        __syncthreads();
        p ^= 1;
    }

    // epilogue: normalize (l in q=c layout -> shuffle to o-layout q=4g+r)
    unsigned short* op = attn_b + ((size_t)b * TT + q0w) * EE + h * HD;
#pragma unroll
    for (int f = 0; f < 2; ++f) {
        const float lf = l_r[f];
        float linv[4];
#pragma unroll
        for (int r = 0; r < 4; ++r) linv[r] = 1.f / __shfl(lf, 20 * g + r);
#pragma unroll
        for (int db = 0; db < 4; ++db)
#pragma unroll
            for (int r = 0; r < 4; ++r)
                op[(size_t)(f * 16 + 4 * g + r) * EE + db * 16 + c] =
                    f2bf(o[f][db][r] * linv[r]);
    }
}

extern "C" void kernel_launch(void* const* d_in, const int* in_sizes, int n_in,
                              void* d_out, int out_size, void* d_ws, size_t ws_size,
                              hipStream_t stream) {
    const float* x     = (const float*)d_in[0];
    const float* wqkv  = (const float*)d_in[1];
    const float* wproj = (const float*)d_in[2];
    float* out = (float*)d_out;

    unsigned short* ws = (unsigned short*)d_ws;
    unsigned short* q_ws    = ws;                    // [B,H,T,64] (pre-scaled)
    unsigned short* k_ws    = ws + (size_t)BTE;
    unsigned short* v_ws    = ws + 2 * (size_t)BTE;  // [B,H,64,T]
    unsigned short* xb      = ws + 3 * (size_t)BTE;  // [8192][768]
    unsigned short* attn_b  = ws + 4 * (size_t)BTE;  // [8192][768]
    unsigned short* wqkv_t  = ws + 5 * (size_t)BTE;  // [2304][768]
    unsigned short* wproj_t = wqkv_t + (size_t)2304 * 768;

    convx_kernel<<<BTE / 2048, 256, 0, stream>>>(x, xb);
    transw_kernel<<<dim3(2304 / 64, KK / 64), 256, 0, stream>>>(wqkv, wqkv_t, 2304);
    transw_kernel<<<dim3(768 / 64, KK / 64), 256, 0, stream>>>(wproj, wproj_t, 768);

    mfma_gemm_kernel<0><<<dim3(2304 / 128, 8192 / 128), 256, 0, stream>>>(
        xb, wqkv_t, q_ws, k_ws, v_ws, nullptr);
    attn_kernel<<<dim3(TT / 128, HH, BB), 256, 0, stream>>>(q_ws, k_ws, v_ws, attn_b);
    mfma_gemm_kernel<1><<<dim3(EE / 128, 8192 / 128), 256, 0, stream>>>(
        attn_b, wproj_t, nullptr, nullptr, nullptr, out);
}